// Round 1
// baseline (704.900 us; speedup 1.0000x reference)
//
#include <hip/hip_runtime.h>

#define T_TOK 4096
#define D_DIM 1024
#define E_EXP 8
#define H_DIM 2048
#define CAP   8704   // 8192 token-expert slots + 8*64 tile padding
#define TILES_M 136  // CAP/64

typedef __attribute__((ext_vector_type(8))) short bf16x8;
typedef __attribute__((ext_vector_type(4))) short short4v;
typedef __attribute__((ext_vector_type(4))) float f32x4;

union AFrag { bf16x8 v; short4v h[2]; };

__device__ inline unsigned short f2bf(float f) {
    unsigned int u = __float_as_uint(f);
    unsigned int r = (u + 0x7fffu + ((u >> 16) & 1u)) >> 16;
    return (unsigned short)r;
}

// ---------------- fp32 -> bf16 convert (by float4) ----------------
__global__ void cvt_kernel(const float* __restrict__ src,
                           unsigned short* __restrict__ dst, int n4) {
    int i = blockIdx.x * blockDim.x + threadIdx.x;
    int stride = gridDim.x * blockDim.x;
    for (; i < n4; i += stride) {
        float4 v = ((const float4*)src)[i];
        ushort4 o;
        o.x = f2bf(v.x); o.y = f2bf(v.y); o.z = f2bf(v.z); o.w = f2bf(v.w);
        ((ushort4*)dst)[i] = o;
    }
}

// ---------------- gating: logits, top-2, softmax, entropy ----------------
__global__ __launch_bounds__(256) void gating_kernel(
    const float* __restrict__ xf, const float* __restrict__ wg,
    const float* __restrict__ bg, int* __restrict__ tk_e,
    float* __restrict__ tk_g, int* __restrict__ counts,
    float* __restrict__ ent_out)
{
    int wave = threadIdx.x >> 6, lane = threadIdx.x & 63;
    int t = blockIdx.x * 4 + wave;
    const float* xr = xf + (size_t)t * D_DIM;
    float acc[8] = {0.f,0.f,0.f,0.f,0.f,0.f,0.f,0.f};
    for (int i = 0; i < 16; i++) {
        int d = lane + i * 64;
        float xv = xr[d];
        const float4* wr = (const float4*)(wg + (size_t)d * 8);
        float4 w0 = wr[0], w1 = wr[1];
        acc[0] += xv * w0.x; acc[1] += xv * w0.y; acc[2] += xv * w0.z; acc[3] += xv * w0.w;
        acc[4] += xv * w1.x; acc[5] += xv * w1.y; acc[6] += xv * w1.z; acc[7] += xv * w1.w;
    }
    #pragma unroll
    for (int s = 1; s < 64; s <<= 1) {
        #pragma unroll
        for (int e = 0; e < 8; e++) acc[e] += __shfl_xor(acc[e], s, 64);
    }
    if (lane == 0) {
        float l[8];
        #pragma unroll
        for (int e = 0; e < 8; e++) l[e] = acc[e] + bg[e];
        int i0 = 0;
        #pragma unroll
        for (int e = 1; e < 8; e++) if (l[e] > l[i0]) i0 = e;
        int i1 = (i0 == 0) ? 1 : 0;
        #pragma unroll
        for (int e = 0; e < 8; e++) if (e != i0 && l[e] > l[i1]) i1 = e;
        float z  = expf(l[i1] - l[i0]);          // <= 1
        float p0 = 1.0f / (1.0f + z);
        float p1 = z / (1.0f + z);
        float ent = -(p0 * logf(fmaxf(p0, 1e-8f)) + p1 * logf(fmaxf(p1, 1e-8f)));
        atomicAdd(ent_out, ent * (1.0f / T_TOK));
        tk_e[t * 2 + 0] = i0; tk_g[t * 2 + 0] = p0;
        tk_e[t * 2 + 1] = i1; tk_g[t * 2 + 1] = p1;
        atomicAdd(&counts[i0], 1);
        atomicAdd(&counts[i1], 1);
    }
}

// ---------------- padded prefix sum over 8 experts ----------------
__global__ void offsets_kernel(const int* __restrict__ counts,
                               int* __restrict__ off, int* __restrict__ cursor) {
    if (threadIdx.x == 0) {
        int o = 0;
        for (int e = 0; e < E_EXP; e++) {
            off[e] = o;
            cursor[e] = o;
            o += (counts[e] + 63) & ~63;
        }
        off[E_EXP] = o;
    }
}

// ---------------- scatter token-expert pairs into slots ----------------
__global__ void scatter_kernel(const int* __restrict__ tk_e,
                               const float* __restrict__ tk_g,
                               int* __restrict__ cursor,
                               int* __restrict__ slot_token,
                               float* __restrict__ slot_gate)
{
    int i = blockIdx.x * blockDim.x + threadIdx.x;
    if (i < T_TOK * 2) {
        int e = tk_e[i];
        int slot = atomicAdd(&cursor[e], 1);
        slot_token[slot] = i >> 1;
        slot_gate[slot] = tk_g[i];
    }
}

// ---------------- GEMM1: Hb = relu(gather(x) @ w1[e] + b1[e]) ----------------
__global__ __launch_bounds__(256) void gemm1_kernel(
    const unsigned short* __restrict__ xb, const unsigned short* __restrict__ w1b,
    const float* __restrict__ b1, const int* __restrict__ off,
    const int* __restrict__ slot_token, unsigned short* __restrict__ Hb)
{
    int s0 = blockIdx.x * 64;
    if (s0 >= off[E_EXP]) return;
    int e = 0;
    while (s0 >= off[e + 1]) e++;
    int n0 = blockIdx.y * 64;

    __shared__ __align__(16) unsigned short As[64][40];
    __shared__ __align__(16) unsigned short Bs[64][40];
    __shared__ int Ts[64];

    int tid = threadIdx.x;
    if (tid < 64) Ts[tid] = slot_token[s0 + tid];
    __syncthreads();

    int arow = tid >> 2, acol = (tid & 3) * 8;
    int bk = tid >> 3, bn0 = (tid & 7) * 8;
    int wave = tid >> 6, lane = tid & 63;
    int lrow = lane & 15, quad = lane >> 4;

    f32x4 acc[4];
    #pragma unroll
    for (int c = 0; c < 4; c++) acc[c] = (f32x4){0.f, 0.f, 0.f, 0.f};

    const unsigned short* wbase = w1b + (size_t)e * D_DIM * H_DIM;
    int tokA = Ts[arow];
    const unsigned short* aptr = (tokA >= 0) ? (xb + (size_t)tokA * D_DIM + acol) : nullptr;

    for (int k0 = 0; k0 < D_DIM; k0 += 32) {
        uint4 av = make_uint4(0u, 0u, 0u, 0u);
        if (aptr) av = *(const uint4*)(aptr + k0);
        uint4 bv = *(const uint4*)(wbase + (size_t)(k0 + bk) * H_DIM + n0 + bn0);
        __syncthreads();
        *(uint2*)&As[arow][acol]     = make_uint2(av.x, av.y);
        *(uint2*)&As[arow][acol + 4] = make_uint2(av.z, av.w);
        Bs[bn0 + 0][bk] = (unsigned short)(bv.x);
        Bs[bn0 + 1][bk] = (unsigned short)(bv.x >> 16);
        Bs[bn0 + 2][bk] = (unsigned short)(bv.y);
        Bs[bn0 + 3][bk] = (unsigned short)(bv.y >> 16);
        Bs[bn0 + 4][bk] = (unsigned short)(bv.z);
        Bs[bn0 + 5][bk] = (unsigned short)(bv.z >> 16);
        Bs[bn0 + 6][bk] = (unsigned short)(bv.w);
        Bs[bn0 + 7][bk] = (unsigned short)(bv.w >> 16);
        __syncthreads();
        AFrag a;
        a.h[0] = *(const short4v*)&As[wave * 16 + lrow][quad * 8];
        a.h[1] = *(const short4v*)&As[wave * 16 + lrow][quad * 8 + 4];
        #pragma unroll
        for (int c = 0; c < 4; c++) {
            AFrag b;
            b.h[0] = *(const short4v*)&Bs[c * 16 + lrow][quad * 8];
            b.h[1] = *(const short4v*)&Bs[c * 16 + lrow][quad * 8 + 4];
            acc[c] = __builtin_amdgcn_mfma_f32_16x16x32_bf16(a.v, b.v, acc[c], 0, 0, 0);
        }
    }
    #pragma unroll
    for (int c = 0; c < 4; c++) {
        int h = n0 + c * 16 + lrow;
        float bias = b1[e * H_DIM + h];
        #pragma unroll
        for (int r = 0; r < 4; r++) {
            int m = wave * 16 + quad * 4 + r;
            float v = fmaxf(acc[c][r] + bias, 0.0f);
            Hb[(size_t)(s0 + m) * H_DIM + h] = f2bf(v);
        }
    }
}

// ---------------- GEMM2: out += gate * (Hb @ w2[e] + b2[e]) ----------------
__global__ __launch_bounds__(256) void gemm2_kernel(
    const unsigned short* __restrict__ Hb, const unsigned short* __restrict__ w2b,
    const float* __restrict__ b2, const int* __restrict__ off,
    const int* __restrict__ slot_token, const float* __restrict__ slot_gate,
    float* __restrict__ out)
{
    int s0 = blockIdx.x * 64;
    if (s0 >= off[E_EXP]) return;
    int e = 0;
    while (s0 >= off[e + 1]) e++;
    int n0 = blockIdx.y * 64;

    __shared__ __align__(16) unsigned short As[64][40];
    __shared__ __align__(16) unsigned short Bs[64][40];
    __shared__ int Ts[64];
    __shared__ float Gs[64];

    int tid = threadIdx.x;
    if (tid < 64) { Ts[tid] = slot_token[s0 + tid]; Gs[tid] = slot_gate[s0 + tid]; }
    __syncthreads();

    int arow = tid >> 2, acol = (tid & 3) * 8;
    int bk = tid >> 3, bn0 = (tid & 7) * 8;
    int wave = tid >> 6, lane = tid & 63;
    int lrow = lane & 15, quad = lane >> 4;

    f32x4 acc[4];
    #pragma unroll
    for (int c = 0; c < 4; c++) acc[c] = (f32x4){0.f, 0.f, 0.f, 0.f};

    const unsigned short* wbase = w2b + (size_t)e * H_DIM * D_DIM;
    const unsigned short* aptr = Hb + (size_t)(s0 + arow) * H_DIM + acol;

    for (int k0 = 0; k0 < H_DIM; k0 += 32) {
        uint4 av = *(const uint4*)(aptr + k0);
        uint4 bv = *(const uint4*)(wbase + (size_t)(k0 + bk) * D_DIM + n0 + bn0);
        __syncthreads();
        *(uint2*)&As[arow][acol]     = make_uint2(av.x, av.y);
        *(uint2*)&As[arow][acol + 4] = make_uint2(av.z, av.w);
        Bs[bn0 + 0][bk] = (unsigned short)(bv.x);
        Bs[bn0 + 1][bk] = (unsigned short)(bv.x >> 16);
        Bs[bn0 + 2][bk] = (unsigned short)(bv.y);
        Bs[bn0 + 3][bk] = (unsigned short)(bv.y >> 16);
        Bs[bn0 + 4][bk] = (unsigned short)(bv.z);
        Bs[bn0 + 5][bk] = (unsigned short)(bv.z >> 16);
        Bs[bn0 + 6][bk] = (unsigned short)(bv.w);
        Bs[bn0 + 7][bk] = (unsigned short)(bv.w >> 16);
        __syncthreads();
        AFrag a;
        a.h[0] = *(const short4v*)&As[wave * 16 + lrow][quad * 8];
        a.h[1] = *(const short4v*)&As[wave * 16 + lrow][quad * 8 + 4];
        #pragma unroll
        for (int c = 0; c < 4; c++) {
            AFrag b;
            b.h[0] = *(const short4v*)&Bs[c * 16 + lrow][quad * 8];
            b.h[1] = *(const short4v*)&Bs[c * 16 + lrow][quad * 8 + 4];
            acc[c] = __builtin_amdgcn_mfma_f32_16x16x32_bf16(a.v, b.v, acc[c], 0, 0, 0);
        }
    }
    #pragma unroll
    for (int c = 0; c < 4; c++) {
        int dcol = n0 + c * 16 + lrow;
        float bias = b2[e * D_DIM + dcol];
        #pragma unroll
        for (int r = 0; r < 4; r++) {
            int m = wave * 16 + quad * 4 + r;
            int t = Ts[m];
            if (t >= 0) {
                atomicAdd(&out[(size_t)t * D_DIM + dcol], Gs[m] * (acc[c][r] + bias));
            }
        }
    }
}

extern "C" void kernel_launch(void* const* d_in, const int* in_sizes, int n_in,
                              void* d_out, int out_size, void* d_ws, size_t ws_size,
                              hipStream_t stream)
{
    const float* xf = (const float*)d_in[0];
    const float* wg = (const float*)d_in[1];
    const float* bg = (const float*)d_in[2];
    const float* w1 = (const float*)d_in[3];
    const float* b1 = (const float*)d_in[4];
    const float* w2 = (const float*)d_in[5];
    const float* b2 = (const float*)d_in[6];
    float* out = (float*)d_out;

    char* p = (char*)d_ws;
    int* counts = (int*)p;                              // 8
    int* cursor = counts + 8;                           // 8
    int* off    = cursor + 8;                           // 16 (9 used)
    int* tk_e   = off + 16;                             // 8192
    float* tk_g = (float*)(tk_e + T_TOK * 2);           // 8192
    int* slot_token = (int*)(tk_g + T_TOK * 2);         // 8704
    float* slot_gate = (float*)(slot_token + CAP);      // 8704
    size_t ofs = ((size_t)((char*)(slot_gate + CAP) - p) + 255) & ~(size_t)255;
    unsigned short* xb  = (unsigned short*)(p + ofs); ofs += (size_t)T_TOK * D_DIM * 2;
    unsigned short* w1b = (unsigned short*)(p + ofs); ofs += (size_t)E_EXP * D_DIM * H_DIM * 2;
    unsigned short* w2b = (unsigned short*)(p + ofs); ofs += (size_t)E_EXP * H_DIM * D_DIM * 2;
    unsigned short* Hb  = (unsigned short*)(p + ofs); ofs += (size_t)CAP * H_DIM * 2;

    hipMemsetAsync(counts, 0, 128, stream);                          // counts+cursor+off
    hipMemsetAsync(slot_token, 0xFF, CAP * sizeof(int), stream);     // pad slots = -1
    hipMemsetAsync(d_out, 0, (size_t)out_size * sizeof(float), stream);

    cvt_kernel<<<1024, 256, 0, stream>>>(xf, xb, T_TOK * D_DIM / 4);
    cvt_kernel<<<2048, 256, 0, stream>>>(w1, w1b, E_EXP * D_DIM * H_DIM / 4);
    cvt_kernel<<<2048, 256, 0, stream>>>(w2, w2b, E_EXP * H_DIM * D_DIM / 4);

    gating_kernel<<<T_TOK / 4, 256, 0, stream>>>(xf, wg, bg, tk_e, tk_g, counts,
                                                 out + (size_t)T_TOK * D_DIM);
    offsets_kernel<<<1, 64, 0, stream>>>(counts, off, cursor);
    scatter_kernel<<<(T_TOK * 2) / 256, 256, 0, stream>>>(tk_e, tk_g, cursor,
                                                          slot_token, slot_gate);
    gemm1_kernel<<<dim3(TILES_M, H_DIM / 64), 256, 0, stream>>>(xb, w1b, b1, off,
                                                                slot_token, Hb);
    gemm2_kernel<<<dim3(TILES_M, D_DIM / 64), 256, 0, stream>>>(Hb, w2b, b2, off,
                                                                slot_token, slot_gate, out);
}

// Round 2
// 459.660 us; speedup vs baseline: 1.5335x; 1.5335x over previous
//
#include <hip/hip_runtime.h>

#define T_TOK 4096
#define D_DIM 1024
#define E_EXP 8
#define H_DIM 2048
#define CAP   9216   // 8192 slots + 8*128 tile padding
#define TILES_M 72   // CAP/128

typedef __attribute__((ext_vector_type(8))) short bf16x8;
typedef __attribute__((ext_vector_type(4))) float f32x4;

__device__ inline unsigned short f2bf(float f) {
    unsigned int u = __float_as_uint(f);
    unsigned int r = (u + 0x7fffu + ((u >> 16) & 1u)) >> 16;
    return (unsigned short)r;
}

#define GLD_LDS16(g, l)                                                        \
    __builtin_amdgcn_global_load_lds(                                          \
        (const __attribute__((address_space(1))) void*)(g),                    \
        (__attribute__((address_space(3))) void*)(l), 16, 0, 0)

// ---------------- fp32 -> bf16 convert (by float4) ----------------
__global__ void cvt_kernel(const float* __restrict__ src,
                           unsigned short* __restrict__ dst, int n4) {
    int i = blockIdx.x * blockDim.x + threadIdx.x;
    int stride = gridDim.x * blockDim.x;
    for (; i < n4; i += stride) {
        float4 v = ((const float4*)src)[i];
        ushort4 o;
        o.x = f2bf(v.x); o.y = f2bf(v.y); o.z = f2bf(v.z); o.w = f2bf(v.w);
        ((ushort4*)dst)[i] = o;
    }
}

// ------------- fp32 (R,C) -> bf16 transposed (C,R), per expert -------------
__global__ __launch_bounds__(256) void tcvt_kernel(const float* __restrict__ src,
                                                   unsigned short* __restrict__ dst,
                                                   int R, int C) {
    __shared__ float tile[32][33];
    size_t eo = (size_t)blockIdx.z * R * C;
    src += eo; dst += eo;
    int tx = threadIdx.x & 31, ty = threadIdx.x >> 5;
    int c0 = blockIdx.x * 32, r0 = blockIdx.y * 32;
    #pragma unroll
    for (int i = 0; i < 4; i++)
        tile[ty + i * 8][tx] = src[(size_t)(r0 + ty + i * 8) * C + c0 + tx];
    __syncthreads();
    #pragma unroll
    for (int i = 0; i < 4; i++)
        dst[(size_t)(c0 + ty + i * 8) * R + r0 + tx] = f2bf(tile[tx][ty + i * 8]);
}

// ---------------- gating: logits, top-2, softmax, entropy ----------------
__global__ __launch_bounds__(256) void gating_kernel(
    const float* __restrict__ xf, const float* __restrict__ wg,
    const float* __restrict__ bg, int* __restrict__ tk_e,
    float* __restrict__ tk_g, int* __restrict__ counts,
    float* __restrict__ ent_out)
{
    int wave = threadIdx.x >> 6, lane = threadIdx.x & 63;
    int t = blockIdx.x * 4 + wave;
    const float* xr = xf + (size_t)t * D_DIM;
    float acc[8] = {0.f,0.f,0.f,0.f,0.f,0.f,0.f,0.f};
    for (int i = 0; i < 16; i++) {
        int d = lane + i * 64;
        float xv = xr[d];
        const float4* wr = (const float4*)(wg + (size_t)d * 8);
        float4 w0 = wr[0], w1 = wr[1];
        acc[0] += xv * w0.x; acc[1] += xv * w0.y; acc[2] += xv * w0.z; acc[3] += xv * w0.w;
        acc[4] += xv * w1.x; acc[5] += xv * w1.y; acc[6] += xv * w1.z; acc[7] += xv * w1.w;
    }
    #pragma unroll
    for (int s = 1; s < 64; s <<= 1) {
        #pragma unroll
        for (int e = 0; e < 8; e++) acc[e] += __shfl_xor(acc[e], s, 64);
    }
    if (lane == 0) {
        float l[8];
        #pragma unroll
        for (int e = 0; e < 8; e++) l[e] = acc[e] + bg[e];
        int i0 = 0;
        #pragma unroll
        for (int e = 1; e < 8; e++) if (l[e] > l[i0]) i0 = e;
        int i1 = (i0 == 0) ? 1 : 0;
        #pragma unroll
        for (int e = 0; e < 8; e++) if (e != i0 && l[e] > l[i1]) i1 = e;
        float z  = expf(l[i1] - l[i0]);          // <= 1
        float p0 = 1.0f / (1.0f + z);
        float p1 = z / (1.0f + z);
        float ent = -(p0 * logf(fmaxf(p0, 1e-8f)) + p1 * logf(fmaxf(p1, 1e-8f)));
        atomicAdd(ent_out, ent * (1.0f / T_TOK));
        tk_e[t * 2 + 0] = i0; tk_g[t * 2 + 0] = p0;
        tk_e[t * 2 + 1] = i1; tk_g[t * 2 + 1] = p1;
        atomicAdd(&counts[i0], 1);
        atomicAdd(&counts[i1], 1);
    }
}

// ---------------- padded prefix sum over 8 experts (pad to 128) ----------------
__global__ void offsets_kernel(const int* __restrict__ counts,
                               int* __restrict__ off, int* __restrict__ cursor) {
    if (threadIdx.x == 0) {
        int o = 0;
        for (int e = 0; e < E_EXP; e++) {
            off[e] = o;
            cursor[e] = o;
            o += (counts[e] + 127) & ~127;
        }
        off[E_EXP] = o;
    }
}

// ---------------- scatter token-expert pairs into slots ----------------
__global__ void scatter_kernel(const int* __restrict__ tk_e,
                               const float* __restrict__ tk_g,
                               int* __restrict__ cursor,
                               int* __restrict__ slot_token,
                               float* __restrict__ slot_gate,
                               int* __restrict__ slot_of)
{
    int i = blockIdx.x * blockDim.x + threadIdx.x;
    if (i < T_TOK * 2) {
        int e = tk_e[i];
        int slot = atomicAdd(&cursor[e], 1);
        slot_token[slot] = i >> 1;
        slot_gate[slot] = tk_g[i];
        slot_of[i] = slot;
    }
}

// ---------------- GEMM1: Hb = relu(gather(x) @ w1t[e]^T + b1[e]) ----------------
// A: gathered xb rows [128 x K], B: w1t rows (n-major, k-contiguous) [128 x K]
__global__ __launch_bounds__(256) void gemm1_kernel(
    const unsigned short* __restrict__ xb, const unsigned short* __restrict__ w1t,
    const float* __restrict__ b1g, const int* __restrict__ off,
    const int* __restrict__ slot_token, unsigned short* __restrict__ Hb)
{
    __shared__ __align__(16) unsigned short As[128 * 32];
    __shared__ __align__(16) unsigned short Bs[128 * 32];

    int s0 = blockIdx.x * 128;
    if (s0 >= off[E_EXP]) return;
    int e = 0;
    while (s0 >= off[e + 1]) e++;
    int n0 = blockIdx.y * 128;

    int tid = threadIdx.x;
    int wave = tid >> 6, lane = tid & 63;
    int lrow = lane & 15, quad = lane >> 4;
    int srow = lane >> 2;          // row within 16-row chunk
    int scol = (lane & 3) * 8;     // shorts (16B units) within 64B row

    int r0 = 32 * wave + srow, r1 = r0 + 16;
    int t0 = slot_token[s0 + r0]; if (t0 < 0) t0 = 0;
    int t1 = slot_token[s0 + r1]; if (t1 < 0) t1 = 0;
    const unsigned short* a0 = xb + (size_t)t0 * D_DIM + scol;
    const unsigned short* a1 = xb + (size_t)t1 * D_DIM + scol;
    const unsigned short* wb = w1t + (size_t)e * H_DIM * D_DIM;
    const unsigned short* bp0 = wb + (size_t)(n0 + r0) * D_DIM + scol;
    const unsigned short* bp1 = wb + (size_t)(n0 + r1) * D_DIM + scol;

    unsigned short* lA0 = As + wave * 1024;   // 2 chunks of 512 shorts per wave
    unsigned short* lA1 = lA0 + 512;
    unsigned short* lB0 = Bs + wave * 1024;
    unsigned short* lB1 = lB0 + 512;

    f32x4 acc[4][4];
    #pragma unroll
    for (int mi = 0; mi < 4; mi++)
        #pragma unroll
        for (int ni = 0; ni < 4; ni++) acc[mi][ni] = (f32x4){0.f, 0.f, 0.f, 0.f};

    int wr = (wave >> 1) * 64, wc = (wave & 1) * 64;

    for (int k0 = 0; k0 < D_DIM; k0 += 32) {
        __syncthreads();
        GLD_LDS16(a0 + k0, lA0);
        GLD_LDS16(a1 + k0, lA1);
        GLD_LDS16(bp0 + k0, lB0);
        GLD_LDS16(bp1 + k0, lB1);
        __syncthreads();
        bf16x8 af[4], bfr[4];
        #pragma unroll
        for (int i = 0; i < 4; i++) {
            af[i]  = *(const bf16x8*)&As[(wr + i * 16 + lrow) * 32 + quad * 8];
            bfr[i] = *(const bf16x8*)&Bs[(wc + i * 16 + lrow) * 32 + quad * 8];
        }
        #pragma unroll
        for (int mi = 0; mi < 4; mi++)
            #pragma unroll
            for (int ni = 0; ni < 4; ni++)
                acc[mi][ni] = __builtin_amdgcn_mfma_f32_16x16x32_bf16(
                    af[mi], bfr[ni], acc[mi][ni], 0, 0, 0);
    }

    #pragma unroll
    for (int ni = 0; ni < 4; ni++) {
        int col = wc + ni * 16 + lrow;
        int h = n0 + col;
        float bv = b1g[e * H_DIM + h];
        #pragma unroll
        for (int mi = 0; mi < 4; mi++) {
            int mrow = wr + mi * 16 + quad * 4;
            #pragma unroll
            for (int r = 0; r < 4; r++) {
                float v = fmaxf(acc[mi][ni][r] + bv, 0.0f);
                Hb[(size_t)(s0 + mrow + r) * H_DIM + h] = f2bf(v);
            }
        }
    }
}

// ---------------- GEMM2: Yb = Hb @ w2t[e]^T + b2[e] (bf16 out) ----------------
__global__ __launch_bounds__(256) void gemm2_kernel(
    const unsigned short* __restrict__ Hb, const unsigned short* __restrict__ w2t,
    const float* __restrict__ b2g, const int* __restrict__ off,
    unsigned short* __restrict__ Yb)
{
    __shared__ __align__(16) unsigned short As[128 * 32];
    __shared__ __align__(16) unsigned short Bs[128 * 32];

    int s0 = blockIdx.x * 128;
    if (s0 >= off[E_EXP]) return;
    int e = 0;
    while (s0 >= off[e + 1]) e++;
    int n0 = blockIdx.y * 128;

    int tid = threadIdx.x;
    int wave = tid >> 6, lane = tid & 63;
    int lrow = lane & 15, quad = lane >> 4;
    int srow = lane >> 2;
    int scol = (lane & 3) * 8;

    int r0 = 32 * wave + srow, r1 = r0 + 16;
    const unsigned short* a0 = Hb + (size_t)(s0 + r0) * H_DIM + scol;
    const unsigned short* a1 = Hb + (size_t)(s0 + r1) * H_DIM + scol;
    const unsigned short* wb = w2t + (size_t)e * D_DIM * H_DIM;
    const unsigned short* bp0 = wb + (size_t)(n0 + r0) * H_DIM + scol;
    const unsigned short* bp1 = wb + (size_t)(n0 + r1) * H_DIM + scol;

    unsigned short* lA0 = As + wave * 1024;
    unsigned short* lA1 = lA0 + 512;
    unsigned short* lB0 = Bs + wave * 1024;
    unsigned short* lB1 = lB0 + 512;

    f32x4 acc[4][4];
    #pragma unroll
    for (int mi = 0; mi < 4; mi++)
        #pragma unroll
        for (int ni = 0; ni < 4; ni++) acc[mi][ni] = (f32x4){0.f, 0.f, 0.f, 0.f};

    int wr = (wave >> 1) * 64, wc = (wave & 1) * 64;

    for (int k0 = 0; k0 < H_DIM; k0 += 32) {
        __syncthreads();
        GLD_LDS16(a0 + k0, lA0);
        GLD_LDS16(a1 + k0, lA1);
        GLD_LDS16(bp0 + k0, lB0);
        GLD_LDS16(bp1 + k0, lB1);
        __syncthreads();
        bf16x8 af[4], bfr[4];
        #pragma unroll
        for (int i = 0; i < 4; i++) {
            af[i]  = *(const bf16x8*)&As[(wr + i * 16 + lrow) * 32 + quad * 8];
            bfr[i] = *(const bf16x8*)&Bs[(wc + i * 16 + lrow) * 32 + quad * 8];
        }
        #pragma unroll
        for (int mi = 0; mi < 4; mi++)
            #pragma unroll
            for (int ni = 0; ni < 4; ni++)
                acc[mi][ni] = __builtin_amdgcn_mfma_f32_16x16x32_bf16(
                    af[mi], bfr[ni], acc[mi][ni], 0, 0, 0);
    }

    #pragma unroll
    for (int ni = 0; ni < 4; ni++) {
        int col = wc + ni * 16 + lrow;
        int d = n0 + col;
        float bv = b2g[e * D_DIM + d];
        #pragma unroll
        for (int mi = 0; mi < 4; mi++) {
            int mrow = wr + mi * 16 + quad * 4;
            #pragma unroll
            for (int r = 0; r < 4; r++) {
                Yb[(size_t)(s0 + mrow + r) * D_DIM + d] = f2bf(acc[mi][ni][r] + bv);
            }
        }
    }
}

// ---------------- combine: out[t] = g0*Y[slot0] + g1*Y[slot1] ----------------
__global__ __launch_bounds__(256) void combine_kernel(
    const unsigned short* __restrict__ Yb, const int* __restrict__ slot_of,
    const float* __restrict__ tk_g, float* __restrict__ out)
{
    int t = blockIdx.x * 2 + (threadIdx.x >> 7);
    int j = threadIdx.x & 127;                 // 8 elements per thread
    int sA = slot_of[t * 2], sB = slot_of[t * 2 + 1];
    float gA = tk_g[t * 2], gB = tk_g[t * 2 + 1];
    uint4 va = *(const uint4*)(Yb + (size_t)sA * D_DIM + j * 8);
    uint4 vb = *(const uint4*)(Yb + (size_t)sB * D_DIM + j * 8);
    const unsigned int* pa = (const unsigned int*)&va;
    const unsigned int* pb = (const unsigned int*)&vb;
    float o[8];
    #pragma unroll
    for (int i = 0; i < 4; i++) {
        float a_lo = __uint_as_float(pa[i] << 16);
        float a_hi = __uint_as_float(pa[i] & 0xffff0000u);
        float b_lo = __uint_as_float(pb[i] << 16);
        float b_hi = __uint_as_float(pb[i] & 0xffff0000u);
        o[i * 2 + 0] = gA * a_lo + gB * b_lo;
        o[i * 2 + 1] = gA * a_hi + gB * b_hi;
    }
    float* op = out + (size_t)t * D_DIM + j * 8;
    ((float4*)op)[0] = make_float4(o[0], o[1], o[2], o[3]);
    ((float4*)op)[1] = make_float4(o[4], o[5], o[6], o[7]);
}

extern "C" void kernel_launch(void* const* d_in, const int* in_sizes, int n_in,
                              void* d_out, int out_size, void* d_ws, size_t ws_size,
                              hipStream_t stream)
{
    const float* xf = (const float*)d_in[0];
    const float* wg = (const float*)d_in[1];
    const float* bg = (const float*)d_in[2];
    const float* w1 = (const float*)d_in[3];
    const float* b1 = (const float*)d_in[4];
    const float* w2 = (const float*)d_in[5];
    const float* b2 = (const float*)d_in[6];
    float* out = (float*)d_out;

    char* p = (char*)d_ws;
    int* counts = (int*)p;                              // 8
    int* cursor = counts + 8;                           // 8
    int* off    = cursor + 8;                           // 16 (9 used)
    int* tk_e   = off + 16;                             // 8192
    float* tk_g = (float*)(tk_e + T_TOK * 2);           // 8192
    int* slot_token = (int*)(tk_g + T_TOK * 2);         // 9216
    float* slot_gate = (float*)(slot_token + CAP);      // 9216
    int* slot_of = (int*)(slot_gate + CAP);             // 8192
    size_t ofs = ((size_t)((char*)(slot_of + T_TOK * 2) - p) + 255) & ~(size_t)255;
    unsigned short* xb  = (unsigned short*)(p + ofs); ofs += (size_t)T_TOK * D_DIM * 2;
    unsigned short* w1t = (unsigned short*)(p + ofs); ofs += (size_t)E_EXP * D_DIM * H_DIM * 2;
    unsigned short* w2t = (unsigned short*)(p + ofs); ofs += (size_t)E_EXP * H_DIM * D_DIM * 2;
    unsigned short* Hb  = (unsigned short*)(p + ofs); ofs += (size_t)CAP * H_DIM * 2;
    unsigned short* Yb  = w1t;   // alias: w1t is dead after gemm1

    hipMemsetAsync(counts, 0, 128, stream);                          // counts+cursor+off
    hipMemsetAsync(slot_token, 0xFF, CAP * sizeof(int), stream);     // pad slots = -1
    hipMemsetAsync(out + (size_t)T_TOK * D_DIM, 0, 4, stream);       // entropy accum

    cvt_kernel<<<1024, 256, 0, stream>>>(xf, xb, T_TOK * D_DIM / 4);
    // w1 (E, D, H) -> w1t (E, H, D)
    tcvt_kernel<<<dim3(H_DIM / 32, D_DIM / 32, E_EXP), 256, 0, stream>>>(w1, w1t, D_DIM, H_DIM);
    // w2 (E, H, D) -> w2t (E, D, H)
    tcvt_kernel<<<dim3(D_DIM / 32, H_DIM / 32, E_EXP), 256, 0, stream>>>(w2, w2t, H_DIM, D_DIM);

    gating_kernel<<<T_TOK / 4, 256, 0, stream>>>(xf, wg, bg, tk_e, tk_g, counts,
                                                 out + (size_t)T_TOK * D_DIM);
    offsets_kernel<<<1, 64, 0, stream>>>(counts, off, cursor);
    scatter_kernel<<<(T_TOK * 2) / 256, 256, 0, stream>>>(tk_e, tk_g, cursor,
                                                          slot_token, slot_gate, slot_of);
    gemm1_kernel<<<dim3(TILES_M, H_DIM / 128), 256, 0, stream>>>(xb, w1t, b1, off,
                                                                 slot_token, Hb);
    gemm2_kernel<<<dim3(TILES_M, D_DIM / 128), 256, 0, stream>>>(Hb, w2t, b2, off, Yb);
    combine_kernel<<<T_TOK / 2, 256, 0, stream>>>(Yb, slot_of, tk_g, out);
}

// Round 3
// 459.610 us; speedup vs baseline: 1.5337x; 1.0001x over previous
//
#include <hip/hip_runtime.h>

#define T_TOK 4096
#define D_DIM 1024
#define E_EXP 8
#define H_DIM 2048
#define CAP   9216   // 8192 slots + 8*128 tile padding
#define TILES_M 72   // CAP/128

typedef __attribute__((ext_vector_type(8))) short bf16x8;
typedef __attribute__((ext_vector_type(4))) float f32x4;

__device__ inline unsigned short f2bf(float f) {
    unsigned int u = __float_as_uint(f);
    unsigned int r = (u + 0x7fffu + ((u >> 16) & 1u)) >> 16;
    return (unsigned short)r;
}

#define GLD_LDS16(g, l)                                                        \
    __builtin_amdgcn_global_load_lds(                                          \
        (const __attribute__((address_space(1))) void*)(g),                    \
        (__attribute__((address_space(3))) void*)(l), 16, 0, 0)

// ---------------- fp32 -> bf16 convert (by float4) ----------------
__global__ void cvt_kernel(const float* __restrict__ src,
                           unsigned short* __restrict__ dst, int n4) {
    int i = blockIdx.x * blockDim.x + threadIdx.x;
    int stride = gridDim.x * blockDim.x;
    for (; i < n4; i += stride) {
        float4 v = ((const float4*)src)[i];
        ushort4 o;
        o.x = f2bf(v.x); o.y = f2bf(v.y); o.z = f2bf(v.z); o.w = f2bf(v.w);
        ((ushort4*)dst)[i] = o;
    }
}

// ------------- fp32 (R,C) -> bf16 transposed (C,R), per expert -------------
// 64x64 tile; float4 loads, ushort4 stores.
__global__ __launch_bounds__(256) void tcvt_kernel(const float* __restrict__ src,
                                                   unsigned short* __restrict__ dst,
                                                   int R, int C) {
    __shared__ float tile[64][65];
    size_t eo = (size_t)blockIdx.z * R * C;
    src += eo; dst += eo;
    int tx = threadIdx.x & 15, ty = threadIdx.x >> 4;
    int c0 = blockIdx.x * 64, r0 = blockIdx.y * 64;
    #pragma unroll
    for (int i = 0; i < 4; i++) {
        int row = ty + i * 16;
        float4 v = *(const float4*)&src[(size_t)(r0 + row) * C + c0 + tx * 4];
        tile[row][tx * 4 + 0] = v.x;
        tile[row][tx * 4 + 1] = v.y;
        tile[row][tx * 4 + 2] = v.z;
        tile[row][tx * 4 + 3] = v.w;
    }
    __syncthreads();
    #pragma unroll
    for (int i = 0; i < 4; i++) {
        int cc = ty + i * 16;
        int rr = tx * 4;
        ushort4 o;
        o.x = f2bf(tile[rr + 0][cc]);
        o.y = f2bf(tile[rr + 1][cc]);
        o.z = f2bf(tile[rr + 2][cc]);
        o.w = f2bf(tile[rr + 3][cc]);
        *(ushort4*)&dst[(size_t)(c0 + cc) * R + r0 + rr] = o;
    }
}

// ---------------- gating: logits, top-2, softmax, entropy partials ----------------
__global__ __launch_bounds__(256) void gating_kernel(
    const float* __restrict__ xf, const float* __restrict__ wg,
    const float* __restrict__ bg, int* __restrict__ tk_e,
    float* __restrict__ tk_g, int* __restrict__ counts,
    float* __restrict__ ent_part)
{
    __shared__ float ents[4];
    int wave = threadIdx.x >> 6, lane = threadIdx.x & 63;
    int t = blockIdx.x * 4 + wave;
    const float* xr = xf + (size_t)t * D_DIM;
    float acc[8] = {0.f,0.f,0.f,0.f,0.f,0.f,0.f,0.f};
    for (int i = 0; i < 16; i++) {
        int d = lane + i * 64;
        float xv = xr[d];
        const float4* wr = (const float4*)(wg + (size_t)d * 8);
        float4 w0 = wr[0], w1 = wr[1];
        acc[0] += xv * w0.x; acc[1] += xv * w0.y; acc[2] += xv * w0.z; acc[3] += xv * w0.w;
        acc[4] += xv * w1.x; acc[5] += xv * w1.y; acc[6] += xv * w1.z; acc[7] += xv * w1.w;
    }
    #pragma unroll
    for (int s = 1; s < 64; s <<= 1) {
        #pragma unroll
        for (int e = 0; e < 8; e++) acc[e] += __shfl_xor(acc[e], s, 64);
    }
    if (lane == 0) {
        float l[8];
        #pragma unroll
        for (int e = 0; e < 8; e++) l[e] = acc[e] + bg[e];
        int i0 = 0;
        #pragma unroll
        for (int e = 1; e < 8; e++) if (l[e] > l[i0]) i0 = e;
        int i1 = (i0 == 0) ? 1 : 0;
        #pragma unroll
        for (int e = 0; e < 8; e++) if (e != i0 && l[e] > l[i1]) i1 = e;
        float z  = expf(l[i1] - l[i0]);          // <= 1
        float p0 = 1.0f / (1.0f + z);
        float p1 = z / (1.0f + z);
        float ent = -(p0 * logf(fmaxf(p0, 1e-8f)) + p1 * logf(fmaxf(p1, 1e-8f)));
        ents[wave] = ent;
        tk_e[t * 2 + 0] = i0; tk_g[t * 2 + 0] = p0;
        tk_e[t * 2 + 1] = i1; tk_g[t * 2 + 1] = p1;
        atomicAdd(&counts[i0], 1);
        atomicAdd(&counts[i1], 1);
    }
    __syncthreads();
    if (threadIdx.x == 0)
        ent_part[blockIdx.x] = ents[0] + ents[1] + ents[2] + ents[3];
}

// ---------------- entropy: reduce 1024 block partials ----------------
__global__ __launch_bounds__(256) void ent_reduce_kernel(
    const float* __restrict__ ent_part, float* __restrict__ ent_out)
{
    __shared__ float ws_[4];
    int tid = threadIdx.x;
    float s = 0.f;
    for (int i = tid; i < T_TOK / 4; i += 256) s += ent_part[i];
    #pragma unroll
    for (int d = 1; d < 64; d <<= 1) s += __shfl_xor(s, d, 64);
    if ((tid & 63) == 0) ws_[tid >> 6] = s;
    __syncthreads();
    if (tid == 0)
        *ent_out = (ws_[0] + ws_[1] + ws_[2] + ws_[3]) * (1.0f / T_TOK);
}

// ---------------- padded prefix sum over 8 experts (pad to 128) ----------------
__global__ void offsets_kernel(const int* __restrict__ counts,
                               int* __restrict__ off, int* __restrict__ cursor) {
    if (threadIdx.x == 0) {
        int o = 0;
        for (int e = 0; e < E_EXP; e++) {
            off[e] = o;
            cursor[e] = o;
            o += (counts[e] + 127) & ~127;
        }
        off[E_EXP] = o;
    }
}

// ---------------- scatter token-expert pairs into slots ----------------
__global__ void scatter_kernel(const int* __restrict__ tk_e,
                               const float* __restrict__ tk_g,
                               int* __restrict__ cursor,
                               int* __restrict__ slot_token,
                               float* __restrict__ slot_gate,
                               int* __restrict__ slot_of)
{
    int i = blockIdx.x * blockDim.x + threadIdx.x;
    if (i < T_TOK * 2) {
        int e = tk_e[i];
        int slot = atomicAdd(&cursor[e], 1);
        slot_token[slot] = i >> 1;
        slot_gate[slot] = tk_g[i];
        slot_of[i] = slot;
    }
}

// ---------------- GEMM1: Hb = relu(gather(x) @ w1t[e]^T + b1[e]) ----------------
__global__ __launch_bounds__(256) void gemm1_kernel(
    const unsigned short* __restrict__ xb, const unsigned short* __restrict__ w1t,
    const float* __restrict__ b1g, const int* __restrict__ off,
    const int* __restrict__ slot_token, unsigned short* __restrict__ Hb)
{
    __shared__ __align__(16) unsigned short As[128 * 32];
    __shared__ __align__(16) unsigned short Bs[128 * 32];

    int s0 = blockIdx.x * 128;
    if (s0 >= off[E_EXP]) return;
    int e = 0;
    while (s0 >= off[e + 1]) e++;
    int n0 = blockIdx.y * 128;

    int tid = threadIdx.x;
    int wave = tid >> 6, lane = tid & 63;
    int lrow = lane & 15, quad = lane >> 4;
    int srow = lane >> 2;          // row within 16-row chunk
    int scol = (lane & 3) * 8;     // shorts (16B units) within 64B row

    int r0 = 32 * wave + srow, r1 = r0 + 16;
    int t0 = slot_token[s0 + r0]; if (t0 < 0) t0 = 0;
    int t1 = slot_token[s0 + r1]; if (t1 < 0) t1 = 0;
    const unsigned short* a0 = xb + (size_t)t0 * D_DIM + scol;
    const unsigned short* a1 = xb + (size_t)t1 * D_DIM + scol;
    const unsigned short* wb = w1t + (size_t)e * H_DIM * D_DIM;
    const unsigned short* bp0 = wb + (size_t)(n0 + r0) * D_DIM + scol;
    const unsigned short* bp1 = wb + (size_t)(n0 + r1) * D_DIM + scol;

    unsigned short* lA0 = As + wave * 1024;   // 2 chunks of 512 shorts per wave
    unsigned short* lA1 = lA0 + 512;
    unsigned short* lB0 = Bs + wave * 1024;
    unsigned short* lB1 = lB0 + 512;

    f32x4 acc[4][4];
    #pragma unroll
    for (int mi = 0; mi < 4; mi++)
        #pragma unroll
        for (int ni = 0; ni < 4; ni++) acc[mi][ni] = (f32x4){0.f, 0.f, 0.f, 0.f};

    int wr = (wave >> 1) * 64, wc = (wave & 1) * 64;

    for (int k0 = 0; k0 < D_DIM; k0 += 32) {
        __syncthreads();
        GLD_LDS16(a0 + k0, lA0);
        GLD_LDS16(a1 + k0, lA1);
        GLD_LDS16(bp0 + k0, lB0);
        GLD_LDS16(bp1 + k0, lB1);
        __syncthreads();
        bf16x8 af[4], bfr[4];
        #pragma unroll
        for (int i = 0; i < 4; i++) {
            af[i]  = *(const bf16x8*)&As[(wr + i * 16 + lrow) * 32 + quad * 8];
            bfr[i] = *(const bf16x8*)&Bs[(wc + i * 16 + lrow) * 32 + quad * 8];
        }
        #pragma unroll
        for (int mi = 0; mi < 4; mi++)
            #pragma unroll
            for (int ni = 0; ni < 4; ni++)
                acc[mi][ni] = __builtin_amdgcn_mfma_f32_16x16x32_bf16(
                    af[mi], bfr[ni], acc[mi][ni], 0, 0, 0);
    }

    #pragma unroll
    for (int ni = 0; ni < 4; ni++) {
        int col = wc + ni * 16 + lrow;
        int h = n0 + col;
        float bv = b1g[e * H_DIM + h];
        #pragma unroll
        for (int mi = 0; mi < 4; mi++) {
            int mrow = wr + mi * 16 + quad * 4;
            #pragma unroll
            for (int r = 0; r < 4; r++) {
                float v = fmaxf(acc[mi][ni][r] + bv, 0.0f);
                Hb[(size_t)(s0 + mrow + r) * H_DIM + h] = f2bf(v);
            }
        }
    }
}

// ---------------- GEMM2: Yb = Hb @ w2t[e]^T + b2[e] (bf16 out) ----------------
__global__ __launch_bounds__(256) void gemm2_kernel(
    const unsigned short* __restrict__ Hb, const unsigned short* __restrict__ w2t,
    const float* __restrict__ b2g, const int* __restrict__ off,
    unsigned short* __restrict__ Yb)
{
    __shared__ __align__(16) unsigned short As[128 * 32];
    __shared__ __align__(16) unsigned short Bs[128 * 32];

    int s0 = blockIdx.x * 128;
    if (s0 >= off[E_EXP]) return;
    int e = 0;
    while (s0 >= off[e + 1]) e++;
    int n0 = blockIdx.y * 128;

    int tid = threadIdx.x;
    int wave = tid >> 6, lane = tid & 63;
    int lrow = lane & 15, quad = lane >> 4;
    int srow = lane >> 2;
    int scol = (lane & 3) * 8;

    int r0 = 32 * wave + srow, r1 = r0 + 16;
    const unsigned short* a0 = Hb + (size_t)(s0 + r0) * H_DIM + scol;
    const unsigned short* a1 = Hb + (size_t)(s0 + r1) * H_DIM + scol;
    const unsigned short* wb = w2t + (size_t)e * D_DIM * H_DIM;
    const unsigned short* bp0 = wb + (size_t)(n0 + r0) * H_DIM + scol;
    const unsigned short* bp1 = wb + (size_t)(n0 + r1) * H_DIM + scol;

    unsigned short* lA0 = As + wave * 1024;
    unsigned short* lA1 = lA0 + 512;
    unsigned short* lB0 = Bs + wave * 1024;
    unsigned short* lB1 = lB0 + 512;

    f32x4 acc[4][4];
    #pragma unroll
    for (int mi = 0; mi < 4; mi++)
        #pragma unroll
        for (int ni = 0; ni < 4; ni++) acc[mi][ni] = (f32x4){0.f, 0.f, 0.f, 0.f};

    int wr = (wave >> 1) * 64, wc = (wave & 1) * 64;

    for (int k0 = 0; k0 < H_DIM; k0 += 32) {
        __syncthreads();
        GLD_LDS16(a0 + k0, lA0);
        GLD_LDS16(a1 + k0, lA1);
        GLD_LDS16(bp0 + k0, lB0);
        GLD_LDS16(bp1 + k0, lB1);
        __syncthreads();
        bf16x8 af[4], bfr[4];
        #pragma unroll
        for (int i = 0; i < 4; i++) {
            af[i]  = *(const bf16x8*)&As[(wr + i * 16 + lrow) * 32 + quad * 8];
            bfr[i] = *(const bf16x8*)&Bs[(wc + i * 16 + lrow) * 32 + quad * 8];
        }
        #pragma unroll
        for (int mi = 0; mi < 4; mi++)
            #pragma unroll
            for (int ni = 0; ni < 4; ni++)
                acc[mi][ni] = __builtin_amdgcn_mfma_f32_16x16x32_bf16(
                    af[mi], bfr[ni], acc[mi][ni], 0, 0, 0);
    }

    #pragma unroll
    for (int ni = 0; ni < 4; ni++) {
        int col = wc + ni * 16 + lrow;
        int d = n0 + col;
        float bv = b2g[e * D_DIM + d];
        #pragma unroll
        for (int mi = 0; mi < 4; mi++) {
            int mrow = wr + mi * 16 + quad * 4;
            #pragma unroll
            for (int r = 0; r < 4; r++) {
                Yb[(size_t)(s0 + mrow + r) * D_DIM + d] = f2bf(acc[mi][ni][r] + bv);
            }
        }
    }
}

// ---------------- combine: out[t] = g0*Y[slot0] + g1*Y[slot1] ----------------
__global__ __launch_bounds__(256) void combine_kernel(
    const unsigned short* __restrict__ Yb, const int* __restrict__ slot_of,
    const float* __restrict__ tk_g, float* __restrict__ out)
{
    int t = blockIdx.x * 2 + (threadIdx.x >> 7);
    int j = threadIdx.x & 127;                 // 8 elements per thread
    int sA = slot_of[t * 2], sB = slot_of[t * 2 + 1];
    float gA = tk_g[t * 2], gB = tk_g[t * 2 + 1];
    uint4 va = *(const uint4*)(Yb + (size_t)sA * D_DIM + j * 8);
    uint4 vb = *(const uint4*)(Yb + (size_t)sB * D_DIM + j * 8);
    const unsigned int* pa = (const unsigned int*)&va;
    const unsigned int* pb = (const unsigned int*)&vb;
    float o[8];
    #pragma unroll
    for (int i = 0; i < 4; i++) {
        float a_lo = __uint_as_float(pa[i] << 16);
        float a_hi = __uint_as_float(pa[i] & 0xffff0000u);
        float b_lo = __uint_as_float(pb[i] << 16);
        float b_hi = __uint_as_float(pb[i] & 0xffff0000u);
        o[i * 2 + 0] = gA * a_lo + gB * b_lo;
        o[i * 2 + 1] = gA * a_hi + gB * b_hi;
    }
    float* op = out + (size_t)t * D_DIM + j * 8;
    ((float4*)op)[0] = make_float4(o[0], o[1], o[2], o[3]);
    ((float4*)op)[1] = make_float4(o[4], o[5], o[6], o[7]);
}

extern "C" void kernel_launch(void* const* d_in, const int* in_sizes, int n_in,
                              void* d_out, int out_size, void* d_ws, size_t ws_size,
                              hipStream_t stream)
{
    const float* xf = (const float*)d_in[0];
    const float* wg = (const float*)d_in[1];
    const float* bg = (const float*)d_in[2];
    const float* w1 = (const float*)d_in[3];
    const float* b1 = (const float*)d_in[4];
    const float* w2 = (const float*)d_in[5];
    const float* b2 = (const float*)d_in[6];
    float* out = (float*)d_out;

    char* p = (char*)d_ws;
    int* counts = (int*)p;                              // 8
    int* cursor = counts + 8;                           // 8
    int* off    = cursor + 8;                           // 16 (9 used)
    int* tk_e   = off + 16;                             // 8192
    float* tk_g = (float*)(tk_e + T_TOK * 2);           // 8192
    int* slot_token = (int*)(tk_g + T_TOK * 2);         // 9216
    float* slot_gate = (float*)(slot_token + CAP);      // 9216
    int* slot_of = (int*)(slot_gate + CAP);             // 8192
    float* ent_part = (float*)(slot_of + T_TOK * 2);    // 1024
    size_t ofs = ((size_t)((char*)(ent_part + T_TOK / 4) - p) + 255) & ~(size_t)255;
    unsigned short* xb  = (unsigned short*)(p + ofs); ofs += (size_t)T_TOK * D_DIM * 2;
    unsigned short* w1t = (unsigned short*)(p + ofs); ofs += (size_t)E_EXP * D_DIM * H_DIM * 2;
    unsigned short* w2t = (unsigned short*)(p + ofs); ofs += (size_t)E_EXP * H_DIM * D_DIM * 2;
    unsigned short* Hb  = (unsigned short*)(p + ofs); ofs += (size_t)CAP * H_DIM * 2;
    unsigned short* Yb  = w1t;   // alias: w1t is dead after gemm1

    hipMemsetAsync(counts, 0, 128, stream);                          // counts+cursor+off
    hipMemsetAsync(slot_token, 0xFF, CAP * sizeof(int), stream);     // pad slots = -1

    cvt_kernel<<<1024, 256, 0, stream>>>(xf, xb, T_TOK * D_DIM / 4);
    // w1 (E, D, H) -> w1t (E, H, D)
    tcvt_kernel<<<dim3(H_DIM / 64, D_DIM / 64, E_EXP), 256, 0, stream>>>(w1, w1t, D_DIM, H_DIM);
    // w2 (E, H, D) -> w2t (E, D, H)
    tcvt_kernel<<<dim3(D_DIM / 64, H_DIM / 64, E_EXP), 256, 0, stream>>>(w2, w2t, H_DIM, D_DIM);

    gating_kernel<<<T_TOK / 4, 256, 0, stream>>>(xf, wg, bg, tk_e, tk_g, counts, ent_part);
    ent_reduce_kernel<<<1, 256, 0, stream>>>(ent_part, out + (size_t)T_TOK * D_DIM);
    offsets_kernel<<<1, 64, 0, stream>>>(counts, off, cursor);
    scatter_kernel<<<(T_TOK * 2) / 256, 256, 0, stream>>>(tk_e, tk_g, cursor,
                                                          slot_token, slot_gate, slot_of);
    gemm1_kernel<<<dim3(TILES_M, H_DIM / 128), 256, 0, stream>>>(xb, w1t, b1, off,
                                                                 slot_token, Hb);
    gemm2_kernel<<<dim3(TILES_M, D_DIM / 128), 256, 0, stream>>>(Hb, w2t, b2, off, Yb);
    combine_kernel<<<T_TOK / 2, 256, 0, stream>>>(Yb, slot_of, tk_g, out);
}

// Round 4
// 341.009 us; speedup vs baseline: 2.0671x; 1.3478x over previous
//
#include <hip/hip_runtime.h>

#define T_TOK 4096
#define D_DIM 1024
#define E_EXP 8
#define H_DIM 2048
#define CAP   9216   // 8192 slots + 8*128 tile padding
#define TILES_M 72   // CAP/128

typedef __attribute__((ext_vector_type(8))) short bf16x8;
typedef __attribute__((ext_vector_type(4))) float f32x4;

__device__ inline unsigned short f2bf(float f) {
    unsigned int u = __float_as_uint(f);
    unsigned int r = (u + 0x7fffu + ((u >> 16) & 1u)) >> 16;
    return (unsigned short)r;
}

#define GLD_LDS16(g, l)                                                        \
    __builtin_amdgcn_global_load_lds(                                          \
        (const __attribute__((address_space(1))) void*)(g),                    \
        (__attribute__((address_space(3))) void*)(l), 16, 0, 0)

// ---------------- fp32 -> bf16 convert (by float4) ----------------
__global__ void cvt_kernel(const float* __restrict__ src,
                           unsigned short* __restrict__ dst, int n4) {
    int i = blockIdx.x * blockDim.x + threadIdx.x;
    int stride = gridDim.x * blockDim.x;
    for (; i < n4; i += stride) {
        float4 v = ((const float4*)src)[i];
        ushort4 o;
        o.x = f2bf(v.x); o.y = f2bf(v.y); o.z = f2bf(v.z); o.w = f2bf(v.w);
        ((ushort4*)dst)[i] = o;
    }
}

// ------------- fp32 (R,C) -> bf16 transposed (C,R), per expert -------------
__global__ __launch_bounds__(256) void tcvt_kernel(const float* __restrict__ src,
                                                   unsigned short* __restrict__ dst,
                                                   int R, int C) {
    __shared__ float tile[64][65];
    size_t eo = (size_t)blockIdx.z * R * C;
    src += eo; dst += eo;
    int tx = threadIdx.x & 15, ty = threadIdx.x >> 4;
    int c0 = blockIdx.x * 64, r0 = blockIdx.y * 64;
    #pragma unroll
    for (int i = 0; i < 4; i++) {
        int row = ty + i * 16;
        float4 v = *(const float4*)&src[(size_t)(r0 + row) * C + c0 + tx * 4];
        tile[row][tx * 4 + 0] = v.x;
        tile[row][tx * 4 + 1] = v.y;
        tile[row][tx * 4 + 2] = v.z;
        tile[row][tx * 4 + 3] = v.w;
    }
    __syncthreads();
    #pragma unroll
    for (int i = 0; i < 4; i++) {
        int cc = ty + i * 16;
        int rr = tx * 4;
        ushort4 o;
        o.x = f2bf(tile[rr + 0][cc]);
        o.y = f2bf(tile[rr + 1][cc]);
        o.z = f2bf(tile[rr + 2][cc]);
        o.w = f2bf(tile[rr + 3][cc]);
        *(ushort4*)&dst[(size_t)(c0 + cc) * R + r0 + rr] = o;
    }
}

// ---------------- gating: logits, top-2, softmax, entropy partials ----------------
// NO atomics (the counts[] atomics serialized on one cache line: ~100us).
__global__ __launch_bounds__(256) void gating_kernel(
    const float* __restrict__ xf, const float* __restrict__ wg,
    const float* __restrict__ bg, int* __restrict__ tk_e,
    float* __restrict__ tk_g, float* __restrict__ ent_part)
{
    __shared__ float ents[4];
    int wave = threadIdx.x >> 6, lane = threadIdx.x & 63;
    int t = blockIdx.x * 4 + wave;
    const float* xr = xf + (size_t)t * D_DIM;
    float acc[8] = {0.f,0.f,0.f,0.f,0.f,0.f,0.f,0.f};
    for (int i = 0; i < 16; i++) {
        int d = lane + i * 64;
        float xv = xr[d];
        const float4* wr = (const float4*)(wg + (size_t)d * 8);
        float4 w0 = wr[0], w1 = wr[1];
        acc[0] += xv * w0.x; acc[1] += xv * w0.y; acc[2] += xv * w0.z; acc[3] += xv * w0.w;
        acc[4] += xv * w1.x; acc[5] += xv * w1.y; acc[6] += xv * w1.z; acc[7] += xv * w1.w;
    }
    #pragma unroll
    for (int s = 1; s < 64; s <<= 1) {
        #pragma unroll
        for (int e = 0; e < 8; e++) acc[e] += __shfl_xor(acc[e], s, 64);
    }
    if (lane == 0) {
        float l[8];
        #pragma unroll
        for (int e = 0; e < 8; e++) l[e] = acc[e] + bg[e];
        int i0 = 0;
        #pragma unroll
        for (int e = 1; e < 8; e++) if (l[e] > l[i0]) i0 = e;
        int i1 = (i0 == 0) ? 1 : 0;
        #pragma unroll
        for (int e = 0; e < 8; e++) if (e != i0 && l[e] > l[i1]) i1 = e;
        float z  = expf(l[i1] - l[i0]);          // <= 1
        float p0 = 1.0f / (1.0f + z);
        float p1 = z / (1.0f + z);
        float ent = -(p0 * logf(fmaxf(p0, 1e-8f)) + p1 * logf(fmaxf(p1, 1e-8f)));
        ents[wave] = ent;
        tk_e[t * 2 + 0] = i0; tk_g[t * 2 + 0] = p0;
        tk_e[t * 2 + 1] = i1; tk_g[t * 2 + 1] = p1;
    }
    __syncthreads();
    if (threadIdx.x == 0)
        ent_part[blockIdx.x] = ents[0] + ents[1] + ents[2] + ents[3];
}

// ---------------- entropy: reduce 1024 block partials ----------------
__global__ __launch_bounds__(256) void ent_reduce_kernel(
    const float* __restrict__ ent_part, float* __restrict__ ent_out)
{
    __shared__ float ws_[4];
    int tid = threadIdx.x;
    float s = 0.f;
    for (int i = tid; i < T_TOK / 4; i += 256) s += ent_part[i];
    #pragma unroll
    for (int d = 1; d < 64; d <<= 1) s += __shfl_xor(s, d, 64);
    if ((tid & 63) == 0) ws_[tid >> 6] = s;
    __syncthreads();
    if (tid == 0)
        *ent_out = (ws_[0] + ws_[1] + ws_[2] + ws_[3]) * (1.0f / T_TOK);
}

// ---------------- routing: count + padded offsets + scatter, atomic-free ----------------
// Single block, 1024 threads (16 waves). Each thread owns 8 consecutive items.
// Per-expert counts packed as 16-bit halves in 4 u32s: e -> reg=(e<4?0:2)+(e&1), half=(e>>1)&1.
__global__ __launch_bounds__(1024) void route_kernel(
    const int* __restrict__ tk_e, const float* __restrict__ tk_g,
    int* __restrict__ off, int* __restrict__ slot_token,
    float* __restrict__ slot_gate, int* __restrict__ slot_of)
{
    __shared__ int wt[16][8];     // per-wave totals
    __shared__ int wx[16][8];     // per-wave exclusive prefix
    __shared__ int base[9];       // padded offsets
    __shared__ int tot[8];        // true counts

    int tid = threadIdx.x, wid = tid >> 6, lane = tid & 63;
    int i0 = tid * 8;
    int ev[8];
    *(int4*)&ev[0] = *(const int4*)&tk_e[i0];
    *(int4*)&ev[4] = *(const int4*)&tk_e[i0 + 4];

    unsigned own[4] = {0u, 0u, 0u, 0u};
    #pragma unroll
    for (int j = 0; j < 8; j++) {
        int e = ev[j];
        int reg = ((e < 4) ? 0 : 2) + (e & 1);
        own[reg] += 1u << (((e >> 1) & 1) * 16);
    }
    unsigned inc[4] = {own[0], own[1], own[2], own[3]};
    #pragma unroll
    for (int d = 1; d < 64; d <<= 1) {
        #pragma unroll
        for (int k = 0; k < 4; k++) {
            unsigned t = __shfl_up(inc[k], d, 64);
            if (lane >= d) inc[k] += t;
        }
    }
    if (lane == 63) {
        #pragma unroll
        for (int e = 0; e < 8; e++) {
            int reg = ((e < 4) ? 0 : 2) + (e & 1);
            wt[wid][e] = (inc[reg] >> (((e >> 1) & 1) * 16)) & 0xFFFF;
        }
    }
    __syncthreads();
    if (tid == 0) {
        int o = 0;
        for (int e = 0; e < 8; e++) {
            int run = 0;
            for (int w = 0; w < 16; w++) { wx[w][e] = run; run += wt[w][e]; }
            tot[e] = run;
            base[e] = o;
            off[e] = o;
            o += (run + 127) & ~127;
        }
        base[8] = o;
        off[8] = o;
    }
    __syncthreads();

    // fill pad slots with -1
    #pragma unroll
    for (int e = 0; e < 8; e++) {
        int p0 = base[e] + tot[e], p1 = base[e + 1];
        for (int i = p0 + tid; i < p1; i += 1024) slot_token[i] = -1;
    }

    // scatter: slot = base[e] + wave_excl + lane_excl + local_running
    unsigned run[4] = {0u, 0u, 0u, 0u};
    #pragma unroll
    for (int j = 0; j < 8; j++) {
        int e = ev[j];
        int reg = ((e < 4) ? 0 : 2) + (e & 1);
        int sh = ((e >> 1) & 1) * 16;
        int lx = (int)(((inc[reg] - own[reg]) >> sh) & 0xFFFF);   // lane exclusive
        int lr = (int)((run[reg] >> sh) & 0xFFFF);                // local running
        int slot = base[e] + wx[wid][e] + lx + lr;
        run[reg] += 1u << sh;
        int i = i0 + j;
        slot_token[slot] = i >> 1;
        slot_gate[slot] = tk_g[i];
        slot_of[i] = slot;
    }
}

// ---------------- GEMM1: Hb = relu(gather(x) @ w1t[e]^T + b1[e]) ----------------
__global__ __launch_bounds__(256) void gemm1_kernel(
    const unsigned short* __restrict__ xb, const unsigned short* __restrict__ w1t,
    const float* __restrict__ b1g, const int* __restrict__ off,
    const int* __restrict__ slot_token, unsigned short* __restrict__ Hb)
{
    __shared__ __align__(16) unsigned short As[128 * 32];
    __shared__ __align__(16) unsigned short Bs[128 * 32];

    int s0 = blockIdx.x * 128;
    if (s0 >= off[E_EXP]) return;
    int e = 0;
    while (s0 >= off[e + 1]) e++;
    int n0 = blockIdx.y * 128;

    int tid = threadIdx.x;
    int wave = tid >> 6, lane = tid & 63;
    int lrow = lane & 15, quad = lane >> 4;
    int srow = lane >> 2;          // row within 16-row chunk
    int scol = (lane & 3) * 8;     // shorts (16B units) within 64B row

    int r0 = 32 * wave + srow, r1 = r0 + 16;
    int t0 = slot_token[s0 + r0]; if (t0 < 0) t0 = 0;
    int t1 = slot_token[s0 + r1]; if (t1 < 0) t1 = 0;
    const unsigned short* a0 = xb + (size_t)t0 * D_DIM + scol;
    const unsigned short* a1 = xb + (size_t)t1 * D_DIM + scol;
    const unsigned short* wb = w1t + (size_t)e * H_DIM * D_DIM;
    const unsigned short* bp0 = wb + (size_t)(n0 + r0) * D_DIM + scol;
    const unsigned short* bp1 = wb + (size_t)(n0 + r1) * D_DIM + scol;

    unsigned short* lA0 = As + wave * 1024;   // 2 chunks of 512 shorts per wave
    unsigned short* lA1 = lA0 + 512;
    unsigned short* lB0 = Bs + wave * 1024;
    unsigned short* lB1 = lB0 + 512;

    f32x4 acc[4][4];
    #pragma unroll
    for (int mi = 0; mi < 4; mi++)
        #pragma unroll
        for (int ni = 0; ni < 4; ni++) acc[mi][ni] = (f32x4){0.f, 0.f, 0.f, 0.f};

    int wr = (wave >> 1) * 64, wc = (wave & 1) * 64;

    for (int k0 = 0; k0 < D_DIM; k0 += 32) {
        __syncthreads();
        GLD_LDS16(a0 + k0, lA0);
        GLD_LDS16(a1 + k0, lA1);
        GLD_LDS16(bp0 + k0, lB0);
        GLD_LDS16(bp1 + k0, lB1);
        __syncthreads();
        bf16x8 af[4], bfr[4];
        #pragma unroll
        for (int i = 0; i < 4; i++) {
            af[i]  = *(const bf16x8*)&As[(wr + i * 16 + lrow) * 32 + quad * 8];
            bfr[i] = *(const bf16x8*)&Bs[(wc + i * 16 + lrow) * 32 + quad * 8];
        }
        #pragma unroll
        for (int mi = 0; mi < 4; mi++)
            #pragma unroll
            for (int ni = 0; ni < 4; ni++)
                acc[mi][ni] = __builtin_amdgcn_mfma_f32_16x16x32_bf16(
                    af[mi], bfr[ni], acc[mi][ni], 0, 0, 0);
    }

    #pragma unroll
    for (int ni = 0; ni < 4; ni++) {
        int col = wc + ni * 16 + lrow;
        int h = n0 + col;
        float bv = b1g[e * H_DIM + h];
        #pragma unroll
        for (int mi = 0; mi < 4; mi++) {
            int mrow = wr + mi * 16 + quad * 4;
            #pragma unroll
            for (int r = 0; r < 4; r++) {
                float v = fmaxf(acc[mi][ni][r] + bv, 0.0f);
                Hb[(size_t)(s0 + mrow + r) * H_DIM + h] = f2bf(v);
            }
        }
    }
}

// ---------------- GEMM2: Yb = Hb @ w2t[e]^T + b2[e] (bf16 out) ----------------
__global__ __launch_bounds__(256) void gemm2_kernel(
    const unsigned short* __restrict__ Hb, const unsigned short* __restrict__ w2t,
    const float* __restrict__ b2g, const int* __restrict__ off,
    unsigned short* __restrict__ Yb)
{
    __shared__ __align__(16) unsigned short As[128 * 32];
    __shared__ __align__(16) unsigned short Bs[128 * 32];

    int s0 = blockIdx.x * 128;
    if (s0 >= off[E_EXP]) return;
    int e = 0;
    while (s0 >= off[e + 1]) e++;
    int n0 = blockIdx.y * 128;

    int tid = threadIdx.x;
    int wave = tid >> 6, lane = tid & 63;
    int lrow = lane & 15, quad = lane >> 4;
    int srow = lane >> 2;
    int scol = (lane & 3) * 8;

    int r0 = 32 * wave + srow, r1 = r0 + 16;
    const unsigned short* a0 = Hb + (size_t)(s0 + r0) * H_DIM + scol;
    const unsigned short* a1 = Hb + (size_t)(s0 + r1) * H_DIM + scol;
    const unsigned short* wb = w2t + (size_t)e * D_DIM * H_DIM;
    const unsigned short* bp0 = wb + (size_t)(n0 + r0) * H_DIM + scol;
    const unsigned short* bp1 = wb + (size_t)(n0 + r1) * H_DIM + scol;

    unsigned short* lA0 = As + wave * 1024;
    unsigned short* lA1 = lA0 + 512;
    unsigned short* lB0 = Bs + wave * 1024;
    unsigned short* lB1 = lB0 + 512;

    f32x4 acc[4][4];
    #pragma unroll
    for (int mi = 0; mi < 4; mi++)
        #pragma unroll
        for (int ni = 0; ni < 4; ni++) acc[mi][ni] = (f32x4){0.f, 0.f, 0.f, 0.f};

    int wr = (wave >> 1) * 64, wc = (wave & 1) * 64;

    for (int k0 = 0; k0 < H_DIM; k0 += 32) {
        __syncthreads();
        GLD_LDS16(a0 + k0, lA0);
        GLD_LDS16(a1 + k0, lA1);
        GLD_LDS16(bp0 + k0, lB0);
        GLD_LDS16(bp1 + k0, lB1);
        __syncthreads();
        bf16x8 af[4], bfr[4];
        #pragma unroll
        for (int i = 0; i < 4; i++) {
            af[i]  = *(const bf16x8*)&As[(wr + i * 16 + lrow) * 32 + quad * 8];
            bfr[i] = *(const bf16x8*)&Bs[(wc + i * 16 + lrow) * 32 + quad * 8];
        }
        #pragma unroll
        for (int mi = 0; mi < 4; mi++)
            #pragma unroll
            for (int ni = 0; ni < 4; ni++)
                acc[mi][ni] = __builtin_amdgcn_mfma_f32_16x16x32_bf16(
                    af[mi], bfr[ni], acc[mi][ni], 0, 0, 0);
    }

    #pragma unroll
    for (int ni = 0; ni < 4; ni++) {
        int col = wc + ni * 16 + lrow;
        int d = n0 + col;
        float bv = b2g[e * D_DIM + d];
        #pragma unroll
        for (int mi = 0; mi < 4; mi++) {
            int mrow = wr + mi * 16 + quad * 4;
            #pragma unroll
            for (int r = 0; r < 4; r++) {
                Yb[(size_t)(s0 + mrow + r) * D_DIM + d] = f2bf(acc[mi][ni][r] + bv);
            }
        }
    }
}

// ---------------- combine: out[t] = g0*Y[slot0] + g1*Y[slot1] ----------------
__global__ __launch_bounds__(256) void combine_kernel(
    const unsigned short* __restrict__ Yb, const int* __restrict__ slot_of,
    const float* __restrict__ tk_g, float* __restrict__ out)
{
    int t = blockIdx.x * 2 + (threadIdx.x >> 7);
    int j = threadIdx.x & 127;                 // 8 elements per thread
    int sA = slot_of[t * 2], sB = slot_of[t * 2 + 1];
    float gA = tk_g[t * 2], gB = tk_g[t * 2 + 1];
    uint4 va = *(const uint4*)(Yb + (size_t)sA * D_DIM + j * 8);
    uint4 vb = *(const uint4*)(Yb + (size_t)sB * D_DIM + j * 8);
    const unsigned int* pa = (const unsigned int*)&va;
    const unsigned int* pb = (const unsigned int*)&vb;
    float o[8];
    #pragma unroll
    for (int i = 0; i < 4; i++) {
        float a_lo = __uint_as_float(pa[i] << 16);
        float a_hi = __uint_as_float(pa[i] & 0xffff0000u);
        float b_lo = __uint_as_float(pb[i] << 16);
        float b_hi = __uint_as_float(pb[i] & 0xffff0000u);
        o[i * 2 + 0] = gA * a_lo + gB * b_lo;
        o[i * 2 + 1] = gA * a_hi + gB * b_hi;
    }
    float* op = out + (size_t)t * D_DIM + j * 8;
    ((float4*)op)[0] = make_float4(o[0], o[1], o[2], o[3]);
    ((float4*)op)[1] = make_float4(o[4], o[5], o[6], o[7]);
}

extern "C" void kernel_launch(void* const* d_in, const int* in_sizes, int n_in,
                              void* d_out, int out_size, void* d_ws, size_t ws_size,
                              hipStream_t stream)
{
    const float* xf = (const float*)d_in[0];
    const float* wg = (const float*)d_in[1];
    const float* bg = (const float*)d_in[2];
    const float* w1 = (const float*)d_in[3];
    const float* b1 = (const float*)d_in[4];
    const float* w2 = (const float*)d_in[5];
    const float* b2 = (const float*)d_in[6];
    float* out = (float*)d_out;

    char* p = (char*)d_ws;
    int* off    = (int*)p;                              // 16 (9 used)
    int* tk_e   = off + 16;                             // 8192
    float* tk_g = (float*)(tk_e + T_TOK * 2);           // 8192
    int* slot_token = (int*)(tk_g + T_TOK * 2);         // 9216
    float* slot_gate = (float*)(slot_token + CAP);      // 9216
    int* slot_of = (int*)(slot_gate + CAP);             // 8192
    float* ent_part = (float*)(slot_of + T_TOK * 2);    // 1024
    size_t ofs = ((size_t)((char*)(ent_part + T_TOK / 4) - p) + 255) & ~(size_t)255;
    unsigned short* xb  = (unsigned short*)(p + ofs); ofs += (size_t)T_TOK * D_DIM * 2;
    unsigned short* w1t = (unsigned short*)(p + ofs); ofs += (size_t)E_EXP * D_DIM * H_DIM * 2;
    unsigned short* w2t = (unsigned short*)(p + ofs); ofs += (size_t)E_EXP * H_DIM * D_DIM * 2;
    unsigned short* Hb  = (unsigned short*)(p + ofs); ofs += (size_t)CAP * H_DIM * 2;
    unsigned short* Yb  = w1t;   // alias: w1t is dead after gemm1

    cvt_kernel<<<1024, 256, 0, stream>>>(xf, xb, T_TOK * D_DIM / 4);
    // w1 (E, D, H) -> w1t (E, H, D)
    tcvt_kernel<<<dim3(H_DIM / 64, D_DIM / 64, E_EXP), 256, 0, stream>>>(w1, w1t, D_DIM, H_DIM);
    // w2 (E, H, D) -> w2t (E, D, H)
    tcvt_kernel<<<dim3(D_DIM / 64, H_DIM / 64, E_EXP), 256, 0, stream>>>(w2, w2t, H_DIM, D_DIM);

    gating_kernel<<<T_TOK / 4, 256, 0, stream>>>(xf, wg, bg, tk_e, tk_g, ent_part);
    ent_reduce_kernel<<<1, 256, 0, stream>>>(ent_part, out + (size_t)T_TOK * D_DIM);
    route_kernel<<<1, 1024, 0, stream>>>(tk_e, tk_g, off, slot_token, slot_gate, slot_of);
    gemm1_kernel<<<dim3(TILES_M, H_DIM / 128), 256, 0, stream>>>(xb, w1t, b1, off,
                                                                 slot_token, Hb);
    gemm2_kernel<<<dim3(TILES_M, D_DIM / 128), 256, 0, stream>>>(Hb, w2t, b2, off, Yb);
    combine_kernel<<<T_TOK / 2, 256, 0, stream>>>(Yb, slot_of, tk_g, out);
}